// Round 1
// baseline (625.720 us; speedup 1.0000x reference)
//
#include <hip/hip_runtime.h>
#include <hip/hip_bf16.h>
#include <stdint.h>

typedef __hip_bfloat16 bf16;
typedef __attribute__((ext_vector_type(8))) short bf16x8;   // 8 bf16 = 4 VGPRs
typedef __attribute__((ext_vector_type(4))) float f32x4;

static constexpr int Mtot = 8192;   // B*T
static constexpr int Ktot = 4096;   // DIN
static constexpr int Ntot = 4096;   // DOUT
static constexpr int BM = 128, BN = 128, BK = 32;

__device__ __forceinline__ void gl_lds16(const void* g, void* l) {
  __builtin_amdgcn_global_load_lds(
      (const __attribute__((address_space(1))) void*)g,
      (__attribute__((address_space(3))) void*)l,
      16, 0, 0);
}

__device__ __forceinline__ uint32_t bf16pair(float a, float b) {
  __hip_bfloat16 ha = __float2bfloat16(a), hb = __float2bfloat16(b);
  uint16_t ia, ib;
  __builtin_memcpy(&ia, &ha, 2);
  __builtin_memcpy(&ib, &hb, 2);
  return (uint32_t)ia | ((uint32_t)ib << 16);
}

// ---------- cast x (fp32 -> bf16), 8 elems/thread ----------
__global__ __launch_bounds__(256) void cast_x_kernel(const float* __restrict__ x,
                                                     bf16* __restrict__ xb) {
  size_t gid = (size_t)blockIdx.x * blockDim.x + threadIdx.x;
  size_t d0 = gid * 8;
  const float4 a = ((const float4*)(x + d0))[0];
  const float4 b = ((const float4*)(x + d0))[1];
  uint4 pk;
  pk.x = bf16pair(a.x, a.y);
  pk.y = bf16pair(a.z, a.w);
  pk.z = bf16pair(b.x, b.y);
  pk.w = bf16pair(b.z, b.w);
  ((uint4*)(xb + d0))[0] = pk;
}

// ---------- W_eff = bf16(W + (U S R) Vh), 8 elems/thread ----------
__global__ __launch_bounds__(256) void prep_w_kernel(const float* __restrict__ W,
                                                     const float* __restrict__ U,
                                                     const float* __restrict__ S,
                                                     const float* __restrict__ Vh,
                                                     const float* __restrict__ P,
                                                     const float* __restrict__ v,
                                                     bf16* __restrict__ Wp) {
  // R = sum_u v[u] * P[u]   (P is [16][2][2] row-major)
  float R0 = 0.f, R1 = 0.f, R2 = 0.f, R3 = 0.f;
#pragma unroll
  for (int u = 0; u < 16; ++u) {
    float vu = v[u];
    R0 += vu * P[u * 4 + 0];
    R1 += vu * P[u * 4 + 1];
    R2 += vu * P[u * 4 + 2];
    R3 += vu * P[u * 4 + 3];
  }
  // SR = S @ R   (S row-major [2][2])
  float SR00 = S[0] * R0 + S[1] * R2, SR01 = S[0] * R1 + S[1] * R3;
  float SR10 = S[2] * R0 + S[3] * R2, SR11 = S[2] * R1 + S[3] * R3;

  int gid = blockIdx.x * blockDim.x + threadIdx.x;  // 4096 * 512 threads
  int o = gid >> 9;
  int d0 = (gid & 511) << 3;
  float u0 = U[o * 2 + 0], u1 = U[o * 2 + 1];
  float M0 = u0 * SR00 + u1 * SR10;   // M[o][0]
  float M1 = u0 * SR01 + u1 * SR11;   // M[o][1]

  const float* wrow = W + (size_t)o * Ktot + d0;
  const float* vh0 = Vh + d0;
  const float* vh1 = Vh + Ktot + d0;
  float val[8];
  const float4 w0 = ((const float4*)wrow)[0];
  const float4 w1 = ((const float4*)wrow)[1];
  const float4 a0 = ((const float4*)vh0)[0];
  const float4 a1 = ((const float4*)vh0)[1];
  const float4 b0 = ((const float4*)vh1)[0];
  const float4 b1 = ((const float4*)vh1)[1];
  val[0] = w0.x + M0 * a0.x + M1 * b0.x;
  val[1] = w0.y + M0 * a0.y + M1 * b0.y;
  val[2] = w0.z + M0 * a0.z + M1 * b0.z;
  val[3] = w0.w + M0 * a0.w + M1 * b0.w;
  val[4] = w1.x + M0 * a1.x + M1 * b1.x;
  val[5] = w1.y + M0 * a1.y + M1 * b1.y;
  val[6] = w1.z + M0 * a1.z + M1 * b1.z;
  val[7] = w1.w + M0 * a1.w + M1 * b1.w;
  uint4 pk;
  pk.x = bf16pair(val[0], val[1]);
  pk.y = bf16pair(val[2], val[3]);
  pk.z = bf16pair(val[4], val[5]);
  pk.w = bf16pair(val[6], val[7]);
  ((uint4*)(Wp + (size_t)o * Ktot + d0))[0] = pk;
}

// ---------- main GEMM: out = A @ Bt^T + bias ----------
// A  : [Mtot][Ktot] bf16 (x)
// Bt : [Ntot][Ktot] bf16 (W_eff, row-major = B^T layout)
__global__ __launch_bounds__(256) void gemm_kernel(const bf16* __restrict__ A,
                                                   const bf16* __restrict__ Bt,
                                                   const float* __restrict__ bias,
                                                   float* __restrict__ out) {
  __shared__ __align__(16) bf16 As[BM * BK];
  __shared__ __align__(16) bf16 Bs[BN * BK];

  const int tid = threadIdx.x;
  const int lane = tid & 63;
  const int wv = tid >> 6;                // 0..3
  const int m0 = blockIdx.y * BM;
  const int n0 = blockIdx.x * BN;

  // staging: each wave covers 32 rows (2 issues of 16 rows x 32 k)
  const int lrow = lane >> 2;             // 0..15
  const int lk = (lane & 3) << 3;         // 0,8,16,24 (elements)

  const bf16* ga0 = A + (size_t)(m0 + wv * 32 + lrow) * Ktot + lk;
  const bf16* ga1 = ga0 + (size_t)16 * Ktot;
  const bf16* gb0 = Bt + (size_t)(n0 + wv * 32 + lrow) * Ktot + lk;
  const bf16* gb1 = gb0 + (size_t)16 * Ktot;
  bf16* la0 = &As[(wv * 32) * BK];
  bf16* la1 = &As[(wv * 32 + 16) * BK];
  bf16* lb0 = &Bs[(wv * 32) * BK];
  bf16* lb1 = &Bs[(wv * 32 + 16) * BK];

  // compute: wave -> 64x64 subtile (4x4 of 16x16)
  const int moff = (wv >> 1) * 64;
  const int noff = (wv & 1) * 64;
  const int fm = lane & 15;
  const int q = lane >> 4;
  const bf16* ra = &As[(moff + fm) * BK + q * 8];
  const bf16* rb = &Bs[(noff + fm) * BK + q * 8];

  f32x4 acc[4][4];
#pragma unroll
  for (int i = 0; i < 4; ++i)
#pragma unroll
    for (int j = 0; j < 4; ++j) acc[i][j] = {0.f, 0.f, 0.f, 0.f};

  for (int kt = 0; kt < Ktot / BK; ++kt) {
    gl_lds16(ga0, la0);
    gl_lds16(ga1, la1);
    gl_lds16(gb0, lb0);
    gl_lds16(gb1, lb1);
    ga0 += BK; ga1 += BK; gb0 += BK; gb1 += BK;
    __syncthreads();   // staging complete (compiler inserts vmcnt(0) drain)

    bf16x8 av[4], bv[4];
#pragma unroll
    for (int i = 0; i < 4; ++i) av[i] = *(const bf16x8*)(ra + i * 16 * BK);
#pragma unroll
    for (int j = 0; j < 4; ++j) bv[j] = *(const bf16x8*)(rb + j * 16 * BK);
#pragma unroll
    for (int i = 0; i < 4; ++i)
#pragma unroll
      for (int j = 0; j < 4; ++j)
        acc[i][j] = __builtin_amdgcn_mfma_f32_16x16x32_bf16(av[i], bv[j], acc[i][j], 0, 0, 0);
    __syncthreads();   // all waves done reading LDS before next overwrite
  }

  // epilogue: C/D layout col = lane&15, row = (lane>>4)*4 + reg
#pragma unroll
  for (int j = 0; j < 4; ++j) {
    const int gn = n0 + noff + j * 16 + fm;
    const float bj = bias[gn];
#pragma unroll
    for (int i = 0; i < 4; ++i) {
      const int gm = m0 + moff + i * 16 + q * 4;
#pragma unroll
      for (int r = 0; r < 4; ++r) {
        out[(size_t)(gm + r) * Ntot + gn] = acc[i][j][r] + bj;
      }
    }
  }
}

extern "C" void kernel_launch(void* const* d_in, const int* in_sizes, int n_in,
                              void* d_out, int out_size, void* d_ws, size_t ws_size,
                              hipStream_t stream) {
  const float* x  = (const float*)d_in[0];
  const float* W  = (const float*)d_in[1];
  const float* b  = (const float*)d_in[2];
  const float* U  = (const float*)d_in[3];
  const float* S  = (const float*)d_in[4];
  const float* Vh = (const float*)d_in[5];
  const float* P  = (const float*)d_in[6];
  const float* v  = (const float*)d_in[7];
  float* out = (float*)d_out;

  bf16* xb = (bf16*)d_ws;                                    // 67,108,864 B
  bf16* Wp = (bf16*)((char*)d_ws + (size_t)Mtot * Ktot * 2); // +33,554,432 B

  cast_x_kernel<<<(Mtot * Ktot / 8) / 256, 256, 0, stream>>>(x, xb);
  prep_w_kernel<<<(Ntot * Ktot / 8) / 256, 256, 0, stream>>>(W, U, S, Vh, P, v, Wp);

  dim3 grid(Ntot / BN, Mtot / BM);  // (32, 64)
  gemm_kernel<<<grid, 256, 0, stream>>>(xb, Wp, b, out);
}

// Round 2
// 614.409 us; speedup vs baseline: 1.0184x; 1.0184x over previous
//
#include <hip/hip_runtime.h>
#include <hip/hip_bf16.h>
#include <stdint.h>

typedef __hip_bfloat16 bf16;
typedef __attribute__((ext_vector_type(8))) short bf16x8;   // 8 bf16 = 4 VGPRs
typedef __attribute__((ext_vector_type(4))) float f32x4;

static constexpr int Mtot = 8192;   // B*T
static constexpr int Ktot = 4096;   // DIN
static constexpr int Ntot = 4096;   // DOUT
static constexpr int BM = 128, BN = 128, BK = 32;
static constexpr int NK = Ktot / BK;            // 128
static constexpr int CAST_BLOCKS = (Mtot * Ktot / 8) / 256;  // 16384
static constexpr int PREP_BLOCKS = (Ntot * Ktot / 8) / 256;  // 2048

__device__ __forceinline__ void gl_lds16(const void* g, void* l) {
  __builtin_amdgcn_global_load_lds(
      (const __attribute__((address_space(1))) void*)g,
      (__attribute__((address_space(3))) void*)l,
      16, 0, 0);
}

__device__ __forceinline__ uint32_t bf16pair(float a, float b) {
  __hip_bfloat16 ha = __float2bfloat16(a), hb = __float2bfloat16(b);
  uint16_t ia, ib;
  __builtin_memcpy(&ia, &ha, 2);
  __builtin_memcpy(&ib, &hb, 2);
  return (uint32_t)ia | ((uint32_t)ib << 16);
}

// ---------- fused prep: cast x -> bf16  AND  W_eff -> bf16 ----------
__global__ __launch_bounds__(256) void prep_kernel(const float* __restrict__ x,
                                                   bf16* __restrict__ xb,
                                                   const float* __restrict__ W,
                                                   const float* __restrict__ U,
                                                   const float* __restrict__ S,
                                                   const float* __restrict__ Vh,
                                                   const float* __restrict__ P,
                                                   const float* __restrict__ v,
                                                   bf16* __restrict__ Wp) {
  const int bid = blockIdx.x;
  if (bid < CAST_BLOCKS) {
    // cast x, 8 elems/thread
    size_t gid = (size_t)bid * 256 + threadIdx.x;
    size_t d0 = gid * 8;
    const float4 a = ((const float4*)(x + d0))[0];
    const float4 b = ((const float4*)(x + d0))[1];
    uint4 pk;
    pk.x = bf16pair(a.x, a.y);
    pk.y = bf16pair(a.z, a.w);
    pk.z = bf16pair(b.x, b.y);
    pk.w = bf16pair(b.z, b.w);
    ((uint4*)(xb + d0))[0] = pk;
  } else {
    // W_eff = bf16(W + (U S R) Vh), 8 elems/thread
    float R0 = 0.f, R1 = 0.f, R2 = 0.f, R3 = 0.f;
#pragma unroll
    for (int u = 0; u < 16; ++u) {
      float vu = v[u];
      R0 += vu * P[u * 4 + 0];
      R1 += vu * P[u * 4 + 1];
      R2 += vu * P[u * 4 + 2];
      R3 += vu * P[u * 4 + 3];
    }
    float SR00 = S[0] * R0 + S[1] * R2, SR01 = S[0] * R1 + S[1] * R3;
    float SR10 = S[2] * R0 + S[3] * R2, SR11 = S[2] * R1 + S[3] * R3;

    int gid = (bid - CAST_BLOCKS) * 256 + threadIdx.x;
    int o = gid >> 9;
    int d0 = (gid & 511) << 3;
    float u0 = U[o * 2 + 0], u1 = U[o * 2 + 1];
    float M0 = u0 * SR00 + u1 * SR10;
    float M1 = u0 * SR01 + u1 * SR11;

    const float* wrow = W + (size_t)o * Ktot + d0;
    const float4 w0 = ((const float4*)wrow)[0];
    const float4 w1 = ((const float4*)wrow)[1];
    const float4 a0 = ((const float4*)(Vh + d0))[0];
    const float4 a1 = ((const float4*)(Vh + d0))[1];
    const float4 b0 = ((const float4*)(Vh + Ktot + d0))[0];
    const float4 b1 = ((const float4*)(Vh + Ktot + d0))[1];
    float val[8];
    val[0] = w0.x + M0 * a0.x + M1 * b0.x;
    val[1] = w0.y + M0 * a0.y + M1 * b0.y;
    val[2] = w0.z + M0 * a0.z + M1 * b0.z;
    val[3] = w0.w + M0 * a0.w + M1 * b0.w;
    val[4] = w1.x + M0 * a1.x + M1 * b1.x;
    val[5] = w1.y + M0 * a1.y + M1 * b1.y;
    val[6] = w1.z + M0 * a1.z + M1 * b1.z;
    val[7] = w1.w + M0 * a1.w + M1 * b1.w;
    uint4 pk;
    pk.x = bf16pair(val[0], val[1]);
    pk.y = bf16pair(val[2], val[3]);
    pk.z = bf16pair(val[4], val[5]);
    pk.w = bf16pair(val[6], val[7]);
    ((uint4*)(Wp + (size_t)o * Ktot + d0))[0] = pk;
  }
}

// ---------- main GEMM: out = A @ Bt^T + bias ----------
// LDS double-buffered; XOR chunk swizzle (chunk' = chunk ^ ((row>>1)&3))
// keeps ds_read_b128 at 2-way bank aliasing (free) while preserving the
// contiguous lane*16 layout global_load_lds requires.
__global__ __launch_bounds__(256) void gemm_kernel(const bf16* __restrict__ A,
                                                   const bf16* __restrict__ Bt,
                                                   const float* __restrict__ bias,
                                                   float* __restrict__ out) {
  __shared__ __align__(16) bf16 As[2][BM * BK];
  __shared__ __align__(16) bf16 Bs[2][BN * BK];

  const int tid = threadIdx.x;
  const int lane = tid & 63;
  const int wv = tid >> 6;                // 0..3
  const int m0 = blockIdx.y * BM;
  const int n0 = blockIdx.x * BN;

  // ---- staging: each wave covers 32 rows (2 issues of 16 rows x 32 k) ----
  const int lrow = lane >> 2;             // 0..15 (row within 16-row chunk)
  // lane's LDS slot is chunk (lane&3) of row lrow; it must hold global
  // chunk (lane&3) ^ s(row), s(row) = (row>>1)&3  (row mod 32 == lrow mod 32
  // for all four staging chunks since their bases are multiples of 16).
  const int lk = (((lane & 3) ^ ((lrow >> 1) & 3)) << 3);  // element offset

  const bf16* ga0 = A + (size_t)(m0 + wv * 32 + lrow) * Ktot + lk;
  const bf16* ga1 = ga0 + (size_t)16 * Ktot;
  const bf16* gb0 = Bt + (size_t)(n0 + wv * 32 + lrow) * Ktot + lk;
  const bf16* gb1 = gb0 + (size_t)16 * Ktot;
  const int laoff0 = (wv * 32) * BK;
  const int laoff1 = (wv * 32 + 16) * BK;

  // ---- compute: wave -> 64x64 subtile (4x4 of 16x16x32) ----
  const int moff = (wv >> 1) * 64;
  const int noff = (wv & 1) * 64;
  const int fm = lane & 15;
  const int q = lane >> 4;                // k-chunk 0..3 wanted
  // stored position of wanted chunk q for row r=(..16k..)+fm: q ^ ((fm>>1)&3)
  const int sw = ((q ^ ((fm >> 1) & 3)) << 3);  // element offset within row

  f32x4 acc[4][4];
#pragma unroll
  for (int i = 0; i < 4; ++i)
#pragma unroll
    for (int j = 0; j < 4; ++j) acc[i][j] = {0.f, 0.f, 0.f, 0.f};

  // prologue: stage tile 0 into buffer 0
  gl_lds16(ga0, &As[0][laoff0]);
  gl_lds16(ga1, &As[0][laoff1]);
  gl_lds16(gb0, &Bs[0][laoff0]);
  gl_lds16(gb1, &Bs[0][laoff1]);
  ga0 += BK; ga1 += BK; gb0 += BK; gb1 += BK;
  __syncthreads();   // drains vmcnt(0): tile 0 resident

  for (int kt = 0; kt < NK; ++kt) {
    const int cur = kt & 1;
    if (kt + 1 < NK) {
      const int nxt = cur ^ 1;
      // issue tile kt+1 loads now; they overlap this tile's ds_read+MFMA
      gl_lds16(ga0, &As[nxt][laoff0]);
      gl_lds16(ga1, &As[nxt][laoff1]);
      gl_lds16(gb0, &Bs[nxt][laoff0]);
      gl_lds16(gb1, &Bs[nxt][laoff1]);
      ga0 += BK; ga1 += BK; gb0 += BK; gb1 += BK;
    }

    const bf16* pa = &As[cur][0];
    const bf16* pb = &Bs[cur][0];
    bf16x8 av[4], bv[4];
#pragma unroll
    for (int i = 0; i < 4; ++i)
      av[i] = *(const bf16x8*)(pa + (moff + i * 16 + fm) * BK + sw);
#pragma unroll
    for (int j = 0; j < 4; ++j)
      bv[j] = *(const bf16x8*)(pb + (noff + j * 16 + fm) * BK + sw);
#pragma unroll
    for (int i = 0; i < 4; ++i)
#pragma unroll
      for (int j = 0; j < 4; ++j)
        acc[i][j] = __builtin_amdgcn_mfma_f32_16x16x32_bf16(av[i], bv[j], acc[i][j], 0, 0, 0);

    __syncthreads();   // readers done with cur; next-tile loads drained
  }

  // epilogue: C/D layout col = lane&15, row = (lane>>4)*4 + reg
#pragma unroll
  for (int j = 0; j < 4; ++j) {
    const int gn = n0 + noff + j * 16 + fm;
    const float bj = bias[gn];
#pragma unroll
    for (int i = 0; i < 4; ++i) {
      const int gm = m0 + moff + i * 16 + q * 4;
#pragma unroll
      for (int r = 0; r < 4; ++r) {
        out[(size_t)(gm + r) * Ntot + gn] = acc[i][j][r] + bj;
      }
    }
  }
}

extern "C" void kernel_launch(void* const* d_in, const int* in_sizes, int n_in,
                              void* d_out, int out_size, void* d_ws, size_t ws_size,
                              hipStream_t stream) {
  const float* x  = (const float*)d_in[0];
  const float* W  = (const float*)d_in[1];
  const float* b  = (const float*)d_in[2];
  const float* U  = (const float*)d_in[3];
  const float* S  = (const float*)d_in[4];
  const float* Vh = (const float*)d_in[5];
  const float* P  = (const float*)d_in[6];
  const float* v  = (const float*)d_in[7];
  float* out = (float*)d_out;

  bf16* xb = (bf16*)d_ws;                                    // 67,108,864 B
  bf16* Wp = (bf16*)((char*)d_ws + (size_t)Mtot * Ktot * 2); // +33,554,432 B

  prep_kernel<<<CAST_BLOCKS + PREP_BLOCKS, 256, 0, stream>>>(x, xb, W, U, S, Vh, P, v, Wp);

  dim3 grid(Ntot / BN, Mtot / BM);  // (32, 64)
  gemm_kernel<<<grid, 256, 0, stream>>>(xb, Wp, b, out);
}